// Round 1
// baseline (790.381 us; speedup 1.0000x reference)
//
#include <hip/hip_runtime.h>
#include <hip/hip_bf16.h>

// SPIL layer: B=8, N=4096, K=32, C=128, H=64, P=32
// R3: persistent double-buffered spil_main. Each block owns 8 tiles (of 4 n's);
//     tile i+1's 64KB nf load is issued before tile i's MFMA and lands in the
//     other LDS region, so HBM streams continuously across the barrier phases.
//     2 barriers/tile; bf16-packed staging regs (32 VGPR); 2 blocks/CU.

#define Bq 8
#define Nq 4096
#define Kq 32
#define Cq 128
#define Hq 64
#define TILES 8          // n-group tiles per block; grid = (B*N/4)/TILES = 1024

typedef __bf16 bf16x8 __attribute__((ext_vector_type(8)));
typedef float  f32x4  __attribute__((ext_vector_type(4)));

__device__ __forceinline__ unsigned short f2bf(float f) {
  __hip_bfloat16 h = __float2bfloat16(f);   // RNE
  return *reinterpret_cast<unsigned short*>(&h);
}
__device__ __forceinline__ float bf2f(unsigned short u) {
  return __uint_as_float(((unsigned int)u) << 16);
}

// ---------- prep 1: WcT[h][c] = [theta|z]^T bf16 ; phiT[h][c] = phi^T bf16 ----------
__global__ __launch_bounds__(256) void prep_w(const float* __restrict__ theta_w,
                                              const float* __restrict__ z_w,
                                              const float* __restrict__ phi_w,
                                              unsigned short* __restrict__ WcT,
                                              unsigned short* __restrict__ phiT) {
  int idx = blockIdx.x * 256 + threadIdx.x;   // 0..24575
  if (idx < 16384) {
    int h = idx >> 7, c = idx & 127;
    float v = (h < 64) ? theta_w[c * 64 + h] : z_w[c * 64 + (h - 64)];
    WcT[idx] = f2bf(v);
  } else {
    int i2 = idx - 16384;                     // 0..8191
    int h = i2 >> 7, c = i2 & 127;
    phiT[i2] = f2bf(phi_w[c * 64 + h]);
  }
}

// ---------- prep 2: phi GEMM: feat = relu(cf @ phi_w + phi_b), + s_i ----------
__global__ __launch_bounds__(256) void phi_gemm(
    const float* __restrict__ cf, const float* __restrict__ cxyz,
    const unsigned short* __restrict__ phiT, const float* __restrict__ phi_b,
    const float* __restrict__ m1_w, const float* __restrict__ m1_b,
    const float* __restrict__ psi_w,
    float* __restrict__ feat_out, float* __restrict__ s_out) {
  __shared__ __align__(16) unsigned short Xs[128 * 128];
  const int t = threadIdx.x;
  const int wave = t >> 6, lane = t & 63;
  const int lo16 = lane & 15, quad = lane >> 4;
  const size_t n0 = (size_t)blockIdx.x * 128;

  bf16x8 wf[4][4];
#pragma unroll
  for (int ks = 0; ks < 4; ks++)
#pragma unroll
    for (int nt = 0; nt < 4; nt++)
      wf[ks][nt] = *(const bf16x8*)(phiT + (size_t)(nt * 16 + lo16) * 128 + ks * 32 + quad * 8);

  const float4* xsrc = (const float4*)(cf + n0 * Cq);
  ushort4* xdst4 = (ushort4*)Xs;
#pragma unroll
  for (int i = 0; i < 16; i++) {
    int j = t + i * 256;
    float4 v = xsrc[j];
    int r = j >> 5, w = j & 31;
    int g = w >> 1, hf = w & 1;
    int p = g ^ (r & 15);
    ushort4 pk;
    pk.x = f2bf(v.x); pk.y = f2bf(v.y); pk.z = f2bf(v.z); pk.w = f2bf(v.w);
    xdst4[r * 32 + p * 2 + hf] = pk;
  }
  __syncthreads();

  f32x4 acc[2][4];
#pragma unroll
  for (int mt = 0; mt < 2; mt++)
#pragma unroll
    for (int nt = 0; nt < 4; nt++) acc[mt][nt] = (f32x4){0.f, 0.f, 0.f, 0.f};
#pragma unroll
  for (int ks = 0; ks < 4; ks++) {
    int p = (ks * 4 + quad) ^ lo16;
    bf16x8 a[2];
#pragma unroll
    for (int mt = 0; mt < 2; mt++) {
      int row = wave * 32 + mt * 16 + lo16;
      a[mt] = *(const bf16x8*)(Xs + row * 128 + p * 8);
    }
#pragma unroll
    for (int mt = 0; mt < 2; mt++)
#pragma unroll
      for (int nt = 0; nt < 4; nt++)
        acc[mt][nt] = __builtin_amdgcn_mfma_f32_16x16x32_bf16(a[mt], wf[ks][nt], acc[mt][nt], 0, 0, 0);
  }

#pragma unroll
  for (int mt = 0; mt < 2; mt++)
#pragma unroll
    for (int nt = 0; nt < 4; nt++) {
      int h = nt * 16 + lo16;
      float b = phi_b[h];
#pragma unroll
      for (int r = 0; r < 4; r++) {
        int row = wave * 32 + mt * 16 + quad * 4 + r;
        feat_out[(n0 + row) * 64 + h] = fmaxf(acc[mt][nt][r] + b, 0.f);
      }
    }

  if (t < 128) {
    size_t n = n0 + t;
    float x = cxyz[n * 3], y = cxyz[n * 3 + 1], z = cxyz[n * 3 + 2];
    float s = 0.f;
#pragma unroll 4
    for (int p = 0; p < 32; p++) {
      float pi = fmaxf(fmaf(x, m1_w[p], fmaf(y, m1_w[32 + p], fmaf(z, m1_w[64 + p], m1_b[p]))), 0.f);
      s = fmaf(pi, psi_w[p], s);
    }
    s_out[n] = s;
  }
}

// ---------- main: persistent pipeline; block handles TILES groups of 4 n's ----------
// LDS 70784B: region[2] x 33792B {Xs[128][128] swizzled bf16 -> outt[128][132] bf16}
//   + feat_d[2][256] f32 + small arrays. 2 blocks/CU.
__global__ __launch_bounds__(256, 2) void spil_main(
    const float* __restrict__ cxyz, const float* __restrict__ nxyz,
    const float* __restrict__ nf,
    const float* __restrict__ theta_b, const float* __restrict__ m2_w,
    const float* __restrict__ m2_b, const float* __restrict__ psi_w,
    const float* __restrict__ psi_b, const float* __restrict__ z_b,
    const unsigned short* __restrict__ WcT,
    const float* __restrict__ feat_i, const float* __restrict__ s_i,
    float* __restrict__ out) {
  __shared__ __align__(16) char smem[70784];
  float* feat_d = (float*)(smem + 67584);                   // [2][256]
  float* m2w_s  = feat_d + 512;                             // 96
  float* m2b_s  = m2w_s + 96;                               // 32
  float* psij_s = m2b_s + 32;                               // 32
  float* zb_s   = psij_s + 32;                              // 64
  float* tb_s   = zb_s + 64;                                // 64 (ends 70784)

  const int t = threadIdx.x;
  const int wave = t >> 6, lane = t & 63;
  const int lo16 = lane & 15, quad = lane >> 4;
  const int mhalf = wave & 1, nhalf = wave >> 1;
  const size_t g0 = (size_t)blockIdx.x * TILES;             // first tile index

  // ---- loop-invariant W fragments (L2-resident 32KB)
  bf16x8 wf[4][4];
#pragma unroll
  for (int ks = 0; ks < 4; ks++)
#pragma unroll
    for (int nt = 0; nt < 4; nt++)
      wf[ks][nt] = *(const bf16x8*)(WcT + (size_t)(nhalf * 64 + nt * 16 + lo16) * 128 + ks * 32 + quad * 8);

  // ---- small epilogue constants
  if (t < 96) m2w_s[t] = m2_w[t];
  if (t < 32) { m2b_s[t] = m2_b[t]; psij_s[t] = psi_w[32 + t]; }
  if (t < 64) { zb_s[t] = z_b[t]; tb_s[t] = theta_b[t]; }

  // ---- prologue: stage tile g0 into region 0
  {
    const float4* xsrc = (const float4*)(nf + g0 * 4 * Kq * Cq);
    ushort4* xd = (ushort4*)smem;
#pragma unroll
    for (int i = 0; i < 16; i++) {
      int j = t + i * 256;
      float4 v = xsrc[j];
      int r = j >> 5, w = j & 31;
      int g = w >> 1, hf = w & 1;
      int p = g ^ (r & 15);
      ushort4 pk;
      pk.x = f2bf(v.x); pk.y = f2bf(v.y); pk.z = f2bf(v.z); pk.w = f2bf(v.w);
      xd[r * 32 + p * 2 + hf] = pk;
    }
    feat_d[t] = feat_i[g0 * 256 + t];
  }
  __syncthreads();

  int cur = 0;
  for (int it = 0; it < TILES; ++it) {
    const size_t gtile = g0 + it;
    const size_t n0 = gtile * 4;
    const bool more = (it + 1 < TILES);

    // ---- issue next tile's loads NOW; convert to bf16 in regs (32 VGPR held)
    ushort4 pk[16];
    if (more) {
      const float4* xsrc = (const float4*)(nf + (n0 + 4) * Kq * Cq);
#pragma unroll
      for (int i = 0; i < 16; i++) {
        float4 v = xsrc[t + i * 256];
        pk[i].x = f2bf(v.x); pk[i].y = f2bf(v.y); pk[i].z = f2bf(v.z); pk[i].w = f2bf(v.w);
      }
    }

    // ---- epilogue operand prefetch for THIS tile (consumed after B2)
    const size_t ng = n0 + wave;
    const int k = lane & 31, half = lane >> 5;
    const float* nxp = nxyz + (ng * Kq + (size_t)k) * 3;
    const float xj = nxp[0], yj = nxp[1], zj = nxp[2];
    const float cx = cxyz[ng * 3], cy = cxyz[ng * 3 + 1], cz = cxyz[ng * 3 + 2];
    const float sI = s_i[ng];

    // ---- MFMA on region[cur]: wave covers 64 rows x 64 cols, K=128
    const unsigned short* Xs = (const unsigned short*)(smem + cur * 33792);
    f32x4 acc[4][4];
#pragma unroll
    for (int mt = 0; mt < 4; mt++)
#pragma unroll
      for (int nt = 0; nt < 4; nt++) acc[mt][nt] = (f32x4){0.f, 0.f, 0.f, 0.f};
#pragma unroll
    for (int ks = 0; ks < 4; ks++) {
      int p = (ks * 4 + quad) ^ lo16;
      bf16x8 a[4];
#pragma unroll
      for (int mt = 0; mt < 4; mt++) {
        int row = mhalf * 64 + mt * 16 + lo16;
        a[mt] = *(const bf16x8*)(Xs + row * 128 + p * 8);
      }
#pragma unroll
      for (int mt = 0; mt < 4; mt++)
#pragma unroll
        for (int nt = 0; nt < 4; nt++)
          acc[mt][nt] = __builtin_amdgcn_mfma_f32_16x16x32_bf16(a[mt], wf[ks][nt], acc[mt][nt], 0, 0, 0);
    }
    __syncthreads();   // B1: Xs[cur] reads done; epilogue(it-1) done

    // ---- C-write into outt[cur] (overwrites dead Xs[cur])
    unsigned short* outt = (unsigned short*)(smem + cur * 33792);
#pragma unroll
    for (int mt = 0; mt < 4; mt++) {
      int row0 = mhalf * 64 + mt * 16 + quad * 4;
#pragma unroll
      for (int nt = 0; nt < 4; nt++) {
        int col = nhalf * 64 + nt * 16 + lo16;
#pragma unroll
        for (int r = 0; r < 4; r++)
          outt[(row0 + r) * 132 + col] = f2bf(acc[mt][nt][r]);
      }
    }

    // ---- commit staged tile it+1 into region[cur^1]
    if (more) {
      ushort4* xd = (ushort4*)(smem + (cur ^ 1) * 33792);
#pragma unroll
      for (int i = 0; i < 16; i++) {
        int j = t + i * 256;
        int r = j >> 5, w = j & 31;
        int g = w >> 1, hf = w & 1;
        int p = g ^ (r & 15);
        xd[r * 32 + p * 2 + hf] = pk[i];
      }
      feat_d[(cur ^ 1) * 256 + t] = feat_i[(gtile + 1) * 256 + t];
    }
    __syncthreads();   // B2: outt[cur] + Xs[cur^1] visible

    // ---- epilogue: wave w handles n = n0 + w; lanes: k = lane&31, h-half = lane>>5
    const float* fi = feat_d + cur * 256 + wave * 64;
    const unsigned short* orow = outt + (size_t)(wave * 32 + k) * 132;
    float vv = 0.f;
#pragma unroll
    for (int i = 0; i < 32; i++) {
      int h = half * 32 + i;
      float fj = fmaxf(bf2f(orow[h]) + tb_s[h], 0.f);
      vv = fmaf(fj, fi[h], vv);
    }
    vv += __shfl_xor(vv, 32);
    float r_f = vv * 0.125f;

    float sj = 0.f;
#pragma unroll
    for (int p = 0; p < 32; p++) {
      float pj = fmaxf(fmaf(xj, m2w_s[p], fmaf(yj, m2w_s[32 + p], fmaf(zj, m2w_s[64 + p], m2b_s[p]))), 0.f);
      sj = fmaf(pj, psij_s[p], sj);
    }
    float rl = fmaxf(sI + sj + psi_b[0], 0.f);
    float dx = cx - xj, dy = cy - yj, dz = cz - zj;
    float dist = sqrtf(dx * dx + dy * dy + dz * dz);
    if (cz == zj && dist > 0.04f) rl = 0.f;   // same_frame && far -> masked

    float m = r_f;
#pragma unroll
    for (int off = 16; off; off >>= 1) m = fmaxf(m, __shfl_xor(m, off));
    float e = rl * __expf(r_f - m);
    float s = e;
#pragma unroll
    for (int off = 16; off; off >>= 1) s += __shfl_xor(s, off);
    float wgt = e / (s + 1e-8f);

    const int h = lane;
    const float zb = zb_s[h];
    float o = 0.f;
#pragma unroll
    for (int kk = 0; kk < 32; kk++) {
      float w = __shfl(wgt, kk);
      o = fmaf(w, bf2f(outt[(wave * 32 + kk) * 132 + 64 + h]) + zb, o);
    }
    out[ng * 64 + h] = o;

    cur ^= 1;
  }
}

extern "C" void kernel_launch(void* const* d_in, const int* in_sizes, int n_in,
                              void* d_out, int out_size, void* d_ws, size_t ws_size,
                              hipStream_t stream) {
  const float* cxyz    = (const float*)d_in[0];
  const float* cf      = (const float*)d_in[1];
  const float* nxyz    = (const float*)d_in[2];
  const float* nf      = (const float*)d_in[3];
  const float* phi_w   = (const float*)d_in[4];
  const float* phi_b   = (const float*)d_in[5];
  const float* theta_w = (const float*)d_in[6];
  const float* theta_b = (const float*)d_in[7];
  const float* m1_w    = (const float*)d_in[8];
  const float* m1_b    = (const float*)d_in[9];
  const float* m2_w    = (const float*)d_in[10];
  const float* m2_b    = (const float*)d_in[11];
  const float* psi_w   = (const float*)d_in[12];
  const float* psi_b   = (const float*)d_in[13];
  const float* z_w     = (const float*)d_in[14];
  const float* z_b     = (const float*)d_in[15];
  float* outp = (float*)d_out;

  // workspace: WcT (32KB) | phiT (16KB) | feat_i (8MB) | s_i (128KB)
  char* ws = (char*)d_ws;
  unsigned short* WcT  = (unsigned short*)ws;
  unsigned short* phiT = (unsigned short*)(ws + 32768);
  float* feat = (float*)(ws + 49152);
  float* s_i  = (float*)(ws + 49152 + (size_t)Bq * Nq * 64 * 4);

  prep_w<<<96, 256, 0, stream>>>(theta_w, z_w, phi_w, WcT, phiT);
  phi_gemm<<<(Bq * Nq) / 128, 256, 0, stream>>>(cf, cxyz, phiT, phi_b, m1_w, m1_b, psi_w, feat, s_i);
  spil_main<<<(Bq * Nq) / 4 / TILES, 256, 0, stream>>>(cxyz, nxyz, nf, theta_b, m2_w, m2_b, psi_w,
                                                       psi_b, z_b, WcT, feat, s_i, outp);
}